// Round 2
// baseline (71.061 us; speedup 1.0000x reference)
//
#include <hip/hip_runtime.h>

// One thread = one sample. 16-amplitude complex state in registers, packed as
// float2 (re,im) so identical re/im arithmetic (RY butterflies, |amp|^2) can
// be emitted as v_pk_fma_f32 (VOP3P).
// Algebraic reductions:
//   - embedding RY(pi*tanh(x)) folded into layer0 RY(w): RY(a)RY(b)=RY(a+b)
//   - product state kept factored through layer0 RZ -> direct tensor build
//   - CNOTs = compile-time register permutations (free)
//   - layer1 RZ dropped (pure phases, killed by |amp|^2)
//   - sum(p)==1 by unitarity -> z_q = 1 - 2*P(bit_q=1)

__device__ __forceinline__ float2 cmul(float2 a, float2 b) {
    return make_float2(fmaf(-a.y, b.y, a.x * b.x),
                       fmaf( a.y, b.x, a.x * b.y));
}

#define CNOT_SWAP(cq, tq)                                               \
    {                                                                   \
        const int cm = 8 >> (cq), tm = 8 >> (tq);                       \
        _Pragma("unroll")                                               \
        for (int n = 0; n < 16; ++n)                                    \
            if ((n & cm) && !(n & tm)) {                                \
                float2 tmp = amp[n]; amp[n] = amp[n | tm]; amp[n | tm] = tmp; \
            }                                                           \
    }

__global__ __launch_bounds__(256) void qcirc_kernel(
    const float* __restrict__ x, const float* __restrict__ w,
    float* __restrict__ out, int B)
{
    int i = blockIdx.x * blockDim.x + threadIdx.x;
    if (i >= B) return;

    // ---- uniform gate coefficients (half-angle cos/sin); w is [2,4,2] ----
    // These are wave-uniform; loads become s_load, trig is unavoidable VALU.
    float Wc[4], Ws[4], Zc[4], Zs[4], C1[4], S1[4];
#pragma unroll
    for (int q = 0; q < 4; ++q) {
        float a = 0.5f * w[2 * q];          // layer0 RY half-angle
        Wc[q] = __cosf(a); Ws[q] = __sinf(a);
        float b = 0.5f * w[2 * q + 1];      // layer0 RZ half-angle
        Zc[q] = __cosf(b); Zs[q] = __sinf(b);
        float c = 0.5f * w[8 + 2 * q];      // layer1 RY half-angle
        C1[q] = __cosf(c); S1[q] = __sinf(c);
    }

    // ---- per-sample angles: x[i, 0..3] (row is 32B; float4 load) ----
    const float4 xv = *reinterpret_cast<const float4*>(x + (size_t)i * 8);
    float xq[4] = {xv.x, xv.y, xv.z, xv.w};

    // per-qubit 1q state after (embed RY + L0 RY + L0 RZ) applied to |0>:
    //   [cos(h+w/2)*e^{-i z/2}, sin(h+w/2)*e^{+i z/2}]
    float2 A[4][2];
#pragma unroll
    for (int q = 0; q < 4; ++q) {
        float e  = __expf(2.f * xq[q]);
        float t  = 1.f - 2.f * __builtin_amdgcn_rcpf(1.f + e);  // tanh(x)
        float h  = 1.57079632679f * t;                          // (pi*tanh)/2
        float cc = __cosf(h), sc = __sinf(h);
        float cq = cc * Wc[q] - sc * Ws[q];   // cos(h + w/2)
        float sq = sc * Wc[q] + cc * Ws[q];   // sin(h + w/2)
        A[q][0] = make_float2(cq * Zc[q], -cq * Zs[q]);
        A[q][1] = make_float2(sq * Zc[q],  sq * Zs[q]);
    }

    // ---- tensor product -> 16 complex amplitudes (qubit0 = MSB) ----
    float2 t01[4], t23[4];
#pragma unroll
    for (int a = 0; a < 2; ++a)
#pragma unroll
        for (int b = 0; b < 2; ++b) {
            t01[a * 2 + b] = cmul(A[0][a], A[1][b]);
            t23[a * 2 + b] = cmul(A[2][a], A[3][b]);
        }

    float2 amp[16];
#pragma unroll
    for (int n = 0; n < 16; ++n)
        amp[n] = cmul(t01[n >> 2], t23[n & 3]);

    // ---- layer0 entangler ----
    CNOT_SWAP(0, 1); CNOT_SWAP(1, 2); CNOT_SWAP(2, 3); CNOT_SWAP(3, 0);

    // ---- layer1 RY: identical real butterfly on re and im (packable) ----
#pragma unroll
    for (int q = 0; q < 4; ++q) {
        const int mask = 8 >> q;
        const float c = C1[q], s = S1[q];
#pragma unroll
        for (int n = 0; n < 16; ++n)
            if (!(n & mask)) {
                const int m = n | mask;
                float2 u = amp[n], v = amp[m];
                amp[n] = make_float2(fmaf(c, u.x, -s * v.x),
                                     fmaf(c, u.y, -s * v.y));
                amp[m] = make_float2(fmaf(s, u.x,  c * v.x),
                                     fmaf(s, u.y,  c * v.y));
            }
    }

    // ---- layer1 entangler (layer1 RZ dropped) ----
    CNOT_SWAP(0, 1); CNOT_SWAP(1, 2); CNOT_SWAP(2, 3); CNOT_SWAP(3, 0);

    // ---- probabilities ----
    float p[16];
#pragma unroll
    for (int n = 0; n < 16; ++n)
        p[n] = fmaf(amp[n].x, amp[n].x, amp[n].y * amp[n].y);

    // ---- z_q = 1 - 2*P(bit_q=1)  (sum p == 1 by unitarity) ----
    float z[4];
#pragma unroll
    for (int q = 0; q < 4; ++q) {
        const int mask = 8 >> q;
        float s1 = 0.f;
#pragma unroll
        for (int n = 0; n < 16; ++n)
            if (n & mask) s1 += p[n];
        z[q] = fmaf(-2.f, s1, 1.f);
    }

    *reinterpret_cast<float4*>(out + (size_t)i * 4) =
        make_float4(z[0], z[1], z[2], z[3]);
}

extern "C" void kernel_launch(void* const* d_in, const int* in_sizes, int n_in,
                              void* d_out, int out_size, void* d_ws, size_t ws_size,
                              hipStream_t stream) {
    const float* x = (const float*)d_in[0];
    const float* w = (const float*)d_in[1];
    float* out = (float*)d_out;
    const int B = in_sizes[0] / 8;          // 524288
    const int threads = 256;
    const int blocks = (B + threads - 1) / threads;
    hipLaunchKernelGGL(qcirc_kernel, dim3(blocks), dim3(threads), 0, stream,
                       x, w, out, B);
}